// Round 1
// baseline (5603.149 us; speedup 1.0000x reference)
//
#include <hip/hip_runtime.h>
#include <cmath>

#define BR 4

__device__ __forceinline__ float sigm(float x) { return 1.0f / (1.0f + expf(-x)); }

// One GRU layer for BR rows, everything workgroup-local.
// in0[r][0:256] = x, in0[r][256:512] = h   (on entry)
// If FIRST: on exit in0[r][0:256] = h1n (unmasked), in0[r][256:512] = h2 (next layer's input)
template<bool FIRST>
__device__ __forceinline__ void gru_layer(
    float (*in0)[512], float (*g)[512], float (*h)[256], float (*hother)[256],
    const float* __restrict__ gk, const float* __restrict__ gb,
    const float* __restrict__ ck, const float* __restrict__ cb,
    int tid, int t, const int* len_s)
{
    // gate: rz = sigmoid([x,h] @ gk + gb); thread tid owns cols tid and tid+256
    float acc0[BR], acc1[BR];
    #pragma unroll
    for (int r = 0; r < BR; ++r) { acc0[r] = 0.f; acc1[r] = 0.f; }
    #pragma unroll 4
    for (int i = 0; i < 512; ++i) {
        float w0  = gk[i * 512 + tid];
        float w1v = gk[i * 512 + 256 + tid];
        #pragma unroll
        for (int r = 0; r < BR; ++r) {
            float xv = in0[r][i];
            acc0[r] = fmaf(xv, w0,  acc0[r]);
            acc1[r] = fmaf(xv, w1v, acc1[r]);
        }
    }
    float bg0 = gb[tid], bg1 = gb[256 + tid];
    #pragma unroll
    for (int r = 0; r < BR; ++r) {
        g[r][tid]       = sigm(acc0[r] + bg0);   // r-gate
        g[r][256 + tid] = sigm(acc1[r] + bg1);   // z-gate
    }
    __syncthreads();                 // all gate dots done reading in0
    #pragma unroll
    for (int r = 0; r < BR; ++r)
        in0[r][256 + tid] = g[r][tid] * h[r][tid];   // cand input = [x, r*h]
    __syncthreads();
    // cand: c = tanh([x, r*h] @ ck + cb); thread tid owns col tid
    float acc[BR];
    #pragma unroll
    for (int r = 0; r < BR; ++r) acc[r] = 0.f;
    #pragma unroll 4
    for (int i = 0; i < 512; ++i) {
        float w = ck[i * 256 + tid];
        #pragma unroll
        for (int r = 0; r < BR; ++r)
            acc[r] = fmaf(in0[r][i], w, acc[r]);
    }
    float bc = cb[tid];
    float hn[BR];
    #pragma unroll
    for (int r = 0; r < BR; ++r) {
        float c = tanhf(acc[r] + bc);
        float z = g[r][256 + tid];
        hn[r] = z * h[r][tid] + (1.f - z) * c;
    }
    __syncthreads();                 // all cand dots done reading in0
    #pragma unroll
    for (int r = 0; r < BR; ++r) {
        if (t < len_s[r]) h[r][tid] = hn[r];   // masked state update
        if constexpr (FIRST) {
            in0[r][tid]       = hn[r];            // layer-2 x = h1n (unmasked, matches ref)
            in0[r][256 + tid] = hother[r][tid];   // layer-2 h = h2
        }
    }
    __syncthreads();
}

// grid = 128 blocks (4 encoders x 32 chunks of BR=4 rows), 256 threads.
// Swizzled so each XCD (blockIdx % 8, assuming round-robin dispatch) runs one encoder:
// that encoder's 3 MB fp32 weights fit the XCD's 4 MiB L2.
__global__ __launch_bounds__(256) void gru_encode(
    const int* __restrict__ iq, const int* __restrict__ ir,
    const int* __restrict__ ql, const int* __restrict__ rl,
    const float* __restrict__ emb,
    const float* __restrict__ gate_k, const float* __restrict__ gate_b,
    const float* __restrict__ cand_k, const float* __restrict__ cand_b,
    float* __restrict__ Qo, float* __restrict__ Ro)
{
    int bid = blockIdx.x;
    int enc   = (bid & 7) >> 1;                 // 0..3
    int chunk = ((bid >> 3) << 1) | (bid & 1);  // 0..31 (bijective)
    int b0 = chunk * BR;
    int tid = threadIdx.x;

    const int* toks = (enc < 2) ? iq : ir;
    const int* lens = (enc < 2) ? ql : rl;
    const bool bw = (enc & 1);

    const float* gk1 = gate_k + (size_t)(enc * 2 + 0) * 512 * 512;
    const float* gk2 = gate_k + (size_t)(enc * 2 + 1) * 512 * 512;
    const float* gb1 = gate_b + (enc * 2 + 0) * 512;
    const float* gb2 = gate_b + (enc * 2 + 1) * 512;
    const float* ck1 = cand_k + (size_t)(enc * 2 + 0) * 512 * 256;
    const float* ck2 = cand_k + (size_t)(enc * 2 + 1) * 512 * 256;
    const float* cb1 = cand_b + (enc * 2 + 0) * 256;
    const float* cb2 = cand_b + (enc * 2 + 1) * 256;

    __shared__ float in0[BR][512];
    __shared__ float g[BR][512];
    __shared__ float h1[BR][256];
    __shared__ float h2[BR][256];
    __shared__ int len_s[BR];

    #pragma unroll
    for (int r = 0; r < BR; ++r) { h1[r][tid] = 0.f; h2[r][tid] = 0.f; }
    if (tid < BR) len_s[tid] = lens[b0 + tid];
    __syncthreads();
    int maxlen = max(max(len_s[0], len_s[1]), max(len_s[2], len_s[3]));

    for (int t = 0; t < maxlen; ++t) {
        #pragma unroll
        for (int r = 0; r < BR; ++r) {
            int len = len_s[r];
            int tt = bw ? ((t < len) ? (len - 1 - t) : t) : t;
            int tok = toks[(b0 + r) * 64 + tt];
            in0[r][tid]       = emb[(size_t)tok * 256 + tid];  // x
            in0[r][256 + tid] = h1[r][tid];                    // h
        }
        __syncthreads();
        gru_layer<true >(in0, g, h1, h2, gk1, gb1, ck1, cb1, tid, t, len_s);
        gru_layer<false>(in0, g, h2, h1, gk2, gb2, ck2, cb2, tid, t, len_s);
    }

    float* outp = (enc < 2) ? Qo : Ro;
    int off = (enc & 1) ? 512 : 0;
    #pragma unroll
    for (int r = 0; r < BR; ++r) {
        int b = b0 + r;
        outp[(size_t)b * 1024 + off + tid]       = h1[r][tid];
        outp[(size_t)b * 1024 + off + 256 + tid] = h2[r][tid];
    }
}

// dist[i][j] = dot(Q[i], R[j]); 16384 threads, one pair each.
__global__ void dist_kernel(const float* __restrict__ Q, const float* __restrict__ R,
                            float* __restrict__ dist)
{
    int gidx = blockIdx.x * 256 + threadIdx.x;   // 0..16383
    int i = gidx >> 7, j = gidx & 127;
    const float4* q4 = (const float4*)(Q + (size_t)i * 1024);
    const float4* r4 = (const float4*)(R + (size_t)j * 1024);
    float acc = 0.f;
    for (int k = 0; k < 256; ++k) {
        float4 a = q4[k], b = r4[k];
        acc += a.x * b.x + a.y * b.y + a.z * b.z + a.w * b.w;
    }
    dist[gidx] = acc;
}

// A = Q @ (Wq + Wdiff), Bv = R @ (Wr - Wdiff)
// grid (4 colblocks, 8 rowblocks, 2 mats), 256 threads; thread owns one col n, 16 rows.
__global__ __launch_bounds__(256) void ab_kernel(
    const float* __restrict__ Q, const float* __restrict__ R,
    const float* __restrict__ w1, float* __restrict__ A, float* __restrict__ Bv)
{
    int nb = blockIdx.x, rb = blockIdx.y, mat = blockIdx.z;
    int tid = threadIdx.x;
    int n = nb * 256 + tid;
    int r0 = rb * 16;
    const float* src   = mat ? R : Q;
    const float* wmain = mat ? (w1 + (size_t)3073 * 1024) : w1;
    const float* wdiff = w1 + (size_t)1025 * 1024;
    float sgn = mat ? -1.f : 1.f;

    __shared__ float Qs[16][64];
    float acc[16];
    #pragma unroll
    for (int r = 0; r < 16; ++r) acc[r] = 0.f;

    for (int k0 = 0; k0 < 1024; k0 += 64) {
        __syncthreads();
        #pragma unroll
        for (int s = 0; s < 4; ++s) {
            int e = s * 256 + tid;
            int r = e >> 6, kk = e & 63;
            Qs[r][kk] = src[(size_t)(r0 + r) * 1024 + k0 + kk];
        }
        __syncthreads();
        for (int kk = 0; kk < 64; ++kk) {
            size_t row = (size_t)(k0 + kk) * 1024 + n;
            float w = wmain[row] + sgn * wdiff[row];
            #pragma unroll
            for (int r = 0; r < 16; ++r)
                acc[r] = fmaf(Qs[r][kk], w, acc[r]);
        }
    }
    float* dst = mat ? Bv : A;
    #pragma unroll
    for (int r = 0; r < 16; ++r)
        dst[(size_t)(r0 + r) * 1024 + n] = acc[r];
}

// C[p][n] = sum_k Q[qi[p]][k]*R[ri[p]][k]*Wprod[k][n]; fused epilogue:
// h = relu(C + A[qi] + Bv[ri] + d*w_d + b1); partial[bn][p][c] = sum_{n in tile} h*w2[n][c]
__global__ __launch_bounds__(256) void pair_gemm(
    const float* __restrict__ Q, const float* __restrict__ R,
    const float* __restrict__ A, const float* __restrict__ Bv,
    const float* __restrict__ dist,
    const int* __restrict__ nqi, const int* __restrict__ nri,
    const float* __restrict__ w1, const float* __restrict__ b1,
    const float* __restrict__ w2, float* __restrict__ partial)
{
    int bm = blockIdx.x;           // 0..255  (64 rows each)
    int bn = blockIdx.y;           // 0..15   (64 cols each)
    int tid = threadIdx.x;
    int tx = tid & 15, ty = tid >> 4;
    int p0 = bm * 64, n0 = bn * 64;

    __shared__ __align__(16) float As[16][68];
    __shared__ __align__(16) float Bs[16][68];
    __shared__ int   qis[64];
    __shared__ int   ris[64];
    __shared__ float ds[64];
    __shared__ float red[256][4][2];

    if (tid < 64) {
        int p = p0 + tid;
        int qi, ri;
        if (p < 128) { qi = p; ri = p; }
        else         { qi = nqi[p - 128]; ri = nri[p - 128]; }
        qis[tid] = qi; ris[tid] = ri; ds[tid] = dist[qi * 128 + ri];
    }
    __syncthreads();

    float acc[4][4];
    #pragma unroll
    for (int r = 0; r < 4; ++r)
        #pragma unroll
        for (int c = 0; c < 4; ++c) acc[r][c] = 0.f;

    int lrow = tid >> 2;      // 0..63
    int kq   = tid & 3;       // 0..3
    const float* wp = w1 + (size_t)2049 * 1024;

    for (int kt = 0; kt < 64; ++kt) {
        int kbase = kt * 16;
        {   // A tile: As[k][m] = Q[qi[m]][kbase+k] * R[ri[m]][kbase+k]
            const float4 q4 = *(const float4*)(Q + (size_t)qis[lrow] * 1024 + kbase + kq * 4);
            const float4 r4 = *(const float4*)(R + (size_t)ris[lrow] * 1024 + kbase + kq * 4);
            As[kq * 4 + 0][lrow] = q4.x * r4.x;
            As[kq * 4 + 1][lrow] = q4.y * r4.y;
            As[kq * 4 + 2][lrow] = q4.z * r4.z;
            As[kq * 4 + 3][lrow] = q4.w * r4.w;
        }
        {   // B tile: Bs[k][n] = Wprod[kbase+k][n0+n]
            int n = tid & 63, kr = tid >> 6;
            #pragma unroll
            for (int s = 0; s < 4; ++s) {
                int k = kr * 4 + s;
                Bs[k][n] = wp[(size_t)(kbase + k) * 1024 + n0 + n];
            }
        }
        __syncthreads();
        #pragma unroll
        for (int k = 0; k < 16; ++k) {
            float4 av = *(const float4*)&As[k][ty * 4];
            float4 bv = *(const float4*)&Bs[k][tx * 4];
            float a[4] = {av.x, av.y, av.z, av.w};
            float b[4] = {bv.x, bv.y, bv.z, bv.w};
            #pragma unroll
            for (int r = 0; r < 4; ++r)
                #pragma unroll
                for (int c = 0; c < 4; ++c)
                    acc[r][c] = fmaf(a[r], b[c], acc[r][c]);
        }
        __syncthreads();
    }

    // epilogue
    float po[4][2] = {{0.f, 0.f}, {0.f, 0.f}, {0.f, 0.f}, {0.f, 0.f}};
    #pragma unroll
    for (int r = 0; r < 4; ++r) {
        int lr = ty * 4 + r;
        int qi = qis[lr], ri = ris[lr];
        float dv = ds[lr];
        #pragma unroll
        for (int c = 0; c < 4; ++c) {
            int n = n0 + tx * 4 + c;
            float h = acc[r][c]
                    + A[(size_t)qi * 1024 + n]
                    + Bv[(size_t)ri * 1024 + n]
                    + dv * w1[(size_t)1024 * 1024 + n]
                    + b1[n];
            h = fmaxf(h, 0.f);
            po[r][0] += h * w2[n * 2 + 0];
            po[r][1] += h * w2[n * 2 + 1];
        }
    }
    #pragma unroll
    for (int r = 0; r < 4; ++r) {
        red[tid][r][0] = po[r][0];
        red[tid][r][1] = po[r][1];
    }
    __syncthreads();
    if (tid < 128) {
        int ty2 = tid >> 3;          // 0..15
        int rr  = (tid >> 1) & 3;    // 0..3
        int cc  = tid & 1;           // 0..1
        float s = 0.f;
        #pragma unroll
        for (int x = 0; x < 16; ++x) s += red[ty2 * 16 + x][rr][cc];
        int p = p0 + ty2 * 4 + rr;
        partial[((size_t)bn * 16384 + p) * 2 + cc] = s;
    }
}

__global__ void final_reduce(const float* __restrict__ partial,
                             const float* __restrict__ b2, float* __restrict__ out)
{
    int gidx = blockIdx.x * 256 + threadIdx.x;   // 0..32767
    int p = gidx >> 1, c = gidx & 1;
    float s = b2[c];
    #pragma unroll
    for (int nt = 0; nt < 16; ++nt)
        s += partial[((size_t)nt * 16384 + p) * 2 + c];
    out[gidx] = s;
}

extern "C" void kernel_launch(void* const* d_in, const int* in_sizes, int n_in,
                              void* d_out, int out_size, void* d_ws, size_t ws_size,
                              hipStream_t stream) {
    const int*   iq     = (const int*)d_in[0];
    const int*   ir     = (const int*)d_in[1];
    const int*   ql     = (const int*)d_in[2];
    const int*   rl     = (const int*)d_in[3];
    const int*   nqi    = (const int*)d_in[4];
    const int*   nri    = (const int*)d_in[5];
    const float* emb    = (const float*)d_in[6];
    const float* gate_k = (const float*)d_in[7];
    const float* gate_b = (const float*)d_in[8];
    const float* cand_k = (const float*)d_in[9];
    const float* cand_b = (const float*)d_in[10];
    const float* w1     = (const float*)d_in[11];
    const float* b1     = (const float*)d_in[12];
    const float* w2     = (const float*)d_in[13];
    const float* b2     = (const float*)d_in[14];
    float* out = (float*)d_out;
    float* ws  = (float*)d_ws;

    float* Q       = ws;                 // 128*1024
    float* R       = ws + 131072;        // 128*1024
    float* A       = ws + 262144;        // 128*1024
    float* Bv      = ws + 393216;        // 128*1024
    float* dist    = ws + 524288;        // 128*128
    float* partial = ws + 540672;        // 16*16384*2

    gru_encode<<<128, 256, 0, stream>>>(iq, ir, ql, rl, emb, gate_k, gate_b,
                                        cand_k, cand_b, Q, R);
    dist_kernel<<<64, 256, 0, stream>>>(Q, R, dist);
    ab_kernel<<<dim3(4, 8, 2), 256, 0, stream>>>(Q, R, w1, A, Bv);
    pair_gemm<<<dim3(256, 16), 256, 0, stream>>>(Q, R, A, Bv, dist, nqi, nri,
                                                 w1, b1, w2, partial);
    final_reduce<<<128, 256, 0, stream>>>(partial, b2, out);
}

// Round 2
// 3029.266 us; speedup vs baseline: 1.8497x; 1.8497x over previous
//
#include <hip/hip_runtime.h>
#include <cmath>

__device__ __forceinline__ float sigm(float x) { return 1.0f / (1.0f + expf(-x)); }

// gate partials: thread (col, q) accumulates gate cols {col, col+256} over i in [q*128, q*128+128)
__device__ __forceinline__ void gate_partial(
    const float (*in0)[512], float (*pr)[4][256], float (*pz)[4][256],
    const float* __restrict__ gk, int col, int q)
{
    float a0[4] = {0.f, 0.f, 0.f, 0.f};
    float a1[4] = {0.f, 0.f, 0.f, 0.f};
    const float* gp = gk + (size_t)(q * 128) * 512 + col;
    const float* x0 = &in0[0][q * 128];
    const float* x1 = &in0[1][q * 128];
    const float* x2 = &in0[2][q * 128];
    const float* x3 = &in0[3][q * 128];
    #pragma unroll 8
    for (int i = 0; i < 128; ++i) {
        float w0 = gp[(size_t)i * 512];
        float w1 = gp[(size_t)i * 512 + 256];
        float v0 = x0[i], v1 = x1[i], v2 = x2[i], v3 = x3[i];
        a0[0] = fmaf(v0, w0, a0[0]); a1[0] = fmaf(v0, w1, a1[0]);
        a0[1] = fmaf(v1, w0, a0[1]); a1[1] = fmaf(v1, w1, a1[1]);
        a0[2] = fmaf(v2, w0, a0[2]); a1[2] = fmaf(v2, w1, a1[2]);
        a0[3] = fmaf(v3, w0, a0[3]); a1[3] = fmaf(v3, w1, a1[3]);
    }
    #pragma unroll
    for (int r = 0; r < 4; ++r) { pr[q][r][col] = a0[r]; pz[q][r][col] = a1[r]; }
}

// cand partials: thread (col, q) accumulates cand col {col} over i in [q*128, q*128+128)
__device__ __forceinline__ void cand_partial(
    const float (*in0)[512], float (*pc)[4][256],
    const float* __restrict__ ck, int col, int q)
{
    float a[4] = {0.f, 0.f, 0.f, 0.f};
    const float* cp = ck + (size_t)(q * 128) * 256 + col;
    const float* x0 = &in0[0][q * 128];
    const float* x1 = &in0[1][q * 128];
    const float* x2 = &in0[2][q * 128];
    const float* x3 = &in0[3][q * 128];
    #pragma unroll 8
    for (int i = 0; i < 128; ++i) {
        float w = cp[(size_t)i * 256];
        a[0] = fmaf(x0[i], w, a[0]);
        a[1] = fmaf(x1[i], w, a[1]);
        a[2] = fmaf(x2[i], w, a[2]);
        a[3] = fmaf(x3[i], w, a[3]);
    }
    #pragma unroll
    for (int r = 0; r < 4; ++r) pc[q][r][col] = a[r];
}

// grid = 128 blocks x 1024 threads. Block = (encoder, chunk of 4 rows); both GRU layers
// are workgroup-local (zero inter-block sync). Thread = (col 0..255, quarter q 0..3);
// the K=512 dot dimension is split 4 ways and reduced through LDS.
// XCD swizzle: bid&7 = XCD (round-robin assumption), 2 XCDs per encoder -> each XCD's
// L2 holds exactly one encoder's 3 MB weight set.
__global__ __launch_bounds__(1024, 4) void gru_encode(
    const int* __restrict__ iq, const int* __restrict__ ir,
    const int* __restrict__ ql, const int* __restrict__ rl,
    const float* __restrict__ emb,
    const float* __restrict__ gate_k, const float* __restrict__ gate_b,
    const float* __restrict__ cand_k, const float* __restrict__ cand_b,
    float* __restrict__ Qo, float* __restrict__ Ro)
{
    int bid = blockIdx.x;
    int xcd = bid & 7;
    int enc = xcd >> 1;                       // 0..3
    int chunk = (xcd & 1) * 16 + (bid >> 3);  // 0..31
    int b0 = chunk * 4;
    int tid = threadIdx.x;
    int col = tid & 255;
    int q = tid >> 8;

    const int* toks = (enc < 2) ? iq : ir;
    const int* lens = (enc < 2) ? ql : rl;
    const bool bw = (enc & 1);

    const float* gk1 = gate_k + (size_t)(enc * 2 + 0) * 512 * 512;
    const float* gk2 = gate_k + (size_t)(enc * 2 + 1) * 512 * 512;
    const float* gb1 = gate_b + (enc * 2 + 0) * 512;
    const float* gb2 = gate_b + (enc * 2 + 1) * 512;
    const float* ck1 = cand_k + (size_t)(enc * 2 + 0) * 512 * 256;
    const float* ck2 = cand_k + (size_t)(enc * 2 + 1) * 512 * 256;
    const float* cb1 = cand_b + (enc * 2 + 0) * 256;
    const float* cb2 = cand_b + (enc * 2 + 1) * 256;

    __shared__ float in0[4][512];
    __shared__ float pr[4][4][256];
    __shared__ float pz[4][4][256];
    __shared__ float pc[4][4][256];
    __shared__ float gz[4][256];
    __shared__ float h1[4][256];
    __shared__ float h2[4][256];
    __shared__ int tok_s[4];
    __shared__ int len_s[4];

    if (q == 0) {
        #pragma unroll
        for (int r = 0; r < 4; ++r) h1[r][col] = 0.f;
    } else if (q == 1) {
        #pragma unroll
        for (int r = 0; r < 4; ++r) h2[r][col] = 0.f;
    }
    if (tid < 4) len_s[tid] = lens[b0 + tid];
    __syncthreads();
    int maxlen = max(max(len_s[0], len_s[1]), max(len_s[2], len_s[3]));
    if (tid < 4) {
        int len = len_s[tid];
        int tt = bw ? ((0 < len) ? (len - 1) : 0) : 0;
        tok_s[tid] = toks[(b0 + tid) * 64 + tt];
    }
    __syncthreads();

    for (int t = 0; t < maxlen; ++t) {
        // FILL: in0 = [x_t, h1]
        if (q == 0) {
            #pragma unroll
            for (int r = 0; r < 4; ++r) in0[r][col] = emb[(size_t)tok_s[r] * 256 + col];
        } else if (q == 1) {
            #pragma unroll
            for (int r = 0; r < 4; ++r) in0[r][256 + col] = h1[r][col];
        }
        __syncthreads();

        // ---- layer 1 ----
        gate_partial(in0, pr, pz, gk1, col, q);
        __syncthreads();
        if (q == 0) {
            #pragma unroll
            for (int r = 0; r < 4; ++r) {
                float rv = sigm(pr[0][r][col] + pr[1][r][col] + pr[2][r][col] + pr[3][r][col] + gb1[col]);
                in0[r][256 + col] = rv * h1[r][col];
            }
        } else if (q == 1) {
            #pragma unroll
            for (int r = 0; r < 4; ++r)
                gz[r][col] = sigm(pz[0][r][col] + pz[1][r][col] + pz[2][r][col] + pz[3][r][col] + gb1[256 + col]);
        }
        __syncthreads();
        cand_partial(in0, pc, ck1, col, q);
        __syncthreads();
        // UPD1: h1 update; in0 <- [h1n (unmasked), h2] for layer 2
        if (q == 0) {
            #pragma unroll
            for (int r = 0; r < 4; ++r) {
                float c = tanhf(pc[0][r][col] + pc[1][r][col] + pc[2][r][col] + pc[3][r][col] + cb1[col]);
                float z = gz[r][col];
                float hv = h1[r][col];
                float hn = fmaf(z, hv - c, c);
                if (t < len_s[r]) h1[r][col] = hn;
                in0[r][col] = hn;
            }
        } else if (q == 1) {
            #pragma unroll
            for (int r = 0; r < 4; ++r) in0[r][256 + col] = h2[r][col];
        }
        __syncthreads();

        // ---- layer 2 ----
        gate_partial(in0, pr, pz, gk2, col, q);
        __syncthreads();
        if (q == 0) {
            #pragma unroll
            for (int r = 0; r < 4; ++r) {
                float rv = sigm(pr[0][r][col] + pr[1][r][col] + pr[2][r][col] + pr[3][r][col] + gb2[col]);
                in0[r][256 + col] = rv * h2[r][col];
            }
        } else if (q == 1) {
            #pragma unroll
            for (int r = 0; r < 4; ++r)
                gz[r][col] = sigm(pz[0][r][col] + pz[1][r][col] + pz[2][r][col] + pz[3][r][col] + gb2[256 + col]);
        }
        __syncthreads();
        cand_partial(in0, pc, ck2, col, q);
        __syncthreads();
        if (q == 0) {
            #pragma unroll
            for (int r = 0; r < 4; ++r) {
                float c = tanhf(pc[0][r][col] + pc[1][r][col] + pc[2][r][col] + pc[3][r][col] + cb2[col]);
                float z = gz[r][col];
                float hv = h2[r][col];
                float hn = fmaf(z, hv - c, c);
                if (t < len_s[r]) h2[r][col] = hn;
            }
        }
        // prefetch next step's tokens
        if (tid < 4) {
            int t2 = t + 1;
            if (t2 < 64) {
                int len = len_s[tid];
                int tt = bw ? ((t2 < len) ? (len - 1 - t2) : t2) : t2;
                tok_s[tid] = toks[(b0 + tid) * 64 + tt];
            }
        }
        __syncthreads();
    }

    float* outp = (enc < 2) ? Qo : Ro;
    int off = (enc & 1) ? 512 : 0;
    if (q == 0) {
        #pragma unroll
        for (int r = 0; r < 4; ++r) {
            int b = b0 + r;
            outp[(size_t)b * 1024 + off + col]       = h1[r][col];
            outp[(size_t)b * 1024 + off + 256 + col] = h2[r][col];
        }
    }
}

// dist[i][j] = dot(Q[i], R[j]); 16384 threads, one pair each.
__global__ void dist_kernel(const float* __restrict__ Q, const float* __restrict__ R,
                            float* __restrict__ dist)
{
    int gidx = blockIdx.x * 256 + threadIdx.x;   // 0..16383
    int i = gidx >> 7, j = gidx & 127;
    const float4* q4 = (const float4*)(Q + (size_t)i * 1024);
    const float4* r4 = (const float4*)(R + (size_t)j * 1024);
    float acc = 0.f;
    for (int k = 0; k < 256; ++k) {
        float4 a = q4[k], b = r4[k];
        acc += a.x * b.x + a.y * b.y + a.z * b.z + a.w * b.w;
    }
    dist[gidx] = acc;
}

// A = Q @ (Wq + Wdiff), Bv = R @ (Wr - Wdiff)
__global__ __launch_bounds__(256) void ab_kernel(
    const float* __restrict__ Q, const float* __restrict__ R,
    const float* __restrict__ w1, float* __restrict__ A, float* __restrict__ Bv)
{
    int nb = blockIdx.x, rb = blockIdx.y, mat = blockIdx.z;
    int tid = threadIdx.x;
    int n = nb * 256 + tid;
    int r0 = rb * 16;
    const float* src   = mat ? R : Q;
    const float* wmain = mat ? (w1 + (size_t)3073 * 1024) : w1;
    const float* wdiff = w1 + (size_t)1025 * 1024;
    float sgn = mat ? -1.f : 1.f;

    __shared__ float Qs[16][64];
    float acc[16];
    #pragma unroll
    for (int r = 0; r < 16; ++r) acc[r] = 0.f;

    for (int k0 = 0; k0 < 1024; k0 += 64) {
        __syncthreads();
        #pragma unroll
        for (int s = 0; s < 4; ++s) {
            int e = s * 256 + tid;
            int r = e >> 6, kk = e & 63;
            Qs[r][kk] = src[(size_t)(r0 + r) * 1024 + k0 + kk];
        }
        __syncthreads();
        for (int kk = 0; kk < 64; ++kk) {
            size_t row = (size_t)(k0 + kk) * 1024 + n;
            float w = wmain[row] + sgn * wdiff[row];
            #pragma unroll
            for (int r = 0; r < 16; ++r)
                acc[r] = fmaf(Qs[r][kk], w, acc[r]);
        }
    }
    float* dst = mat ? Bv : A;
    #pragma unroll
    for (int r = 0; r < 16; ++r)
        dst[(size_t)(r0 + r) * 1024 + n] = acc[r];
}

// C[p][n] = sum_k Q[qi[p]][k]*R[ri[p]][k]*Wprod[k][n]; fused epilogue -> per-N-tile w2 partials
__global__ __launch_bounds__(256) void pair_gemm(
    const float* __restrict__ Q, const float* __restrict__ R,
    const float* __restrict__ A, const float* __restrict__ Bv,
    const float* __restrict__ dist,
    const int* __restrict__ nqi, const int* __restrict__ nri,
    const float* __restrict__ w1, const float* __restrict__ b1,
    const float* __restrict__ w2, float* __restrict__ partial)
{
    int bm = blockIdx.x;           // 0..255  (64 rows each)
    int bn = blockIdx.y;           // 0..15   (64 cols each)
    int tid = threadIdx.x;
    int tx = tid & 15, ty = tid >> 4;
    int p0 = bm * 64, n0 = bn * 64;

    __shared__ __align__(16) float As[16][68];
    __shared__ __align__(16) float Bs[16][68];
    __shared__ int   qis[64];
    __shared__ int   ris[64];
    __shared__ float ds[64];
    __shared__ float red[256][4][2];

    if (tid < 64) {
        int p = p0 + tid;
        int qi, ri;
        if (p < 128) { qi = p; ri = p; }
        else         { qi = nqi[p - 128]; ri = nri[p - 128]; }
        qis[tid] = qi; ris[tid] = ri; ds[tid] = dist[qi * 128 + ri];
    }
    __syncthreads();

    float acc[4][4];
    #pragma unroll
    for (int r = 0; r < 4; ++r)
        #pragma unroll
        for (int c = 0; c < 4; ++c) acc[r][c] = 0.f;

    int lrow = tid >> 2;      // 0..63
    int kq   = tid & 3;       // 0..3
    const float* wp = w1 + (size_t)2049 * 1024;

    for (int kt = 0; kt < 64; ++kt) {
        int kbase = kt * 16;
        {
            const float4 q4 = *(const float4*)(Q + (size_t)qis[lrow] * 1024 + kbase + kq * 4);
            const float4 r4 = *(const float4*)(R + (size_t)ris[lrow] * 1024 + kbase + kq * 4);
            As[kq * 4 + 0][lrow] = q4.x * r4.x;
            As[kq * 4 + 1][lrow] = q4.y * r4.y;
            As[kq * 4 + 2][lrow] = q4.z * r4.z;
            As[kq * 4 + 3][lrow] = q4.w * r4.w;
        }
        {
            int n = tid & 63, kr = tid >> 6;
            #pragma unroll
            for (int s = 0; s < 4; ++s) {
                int k = kr * 4 + s;
                Bs[k][n] = wp[(size_t)(kbase + k) * 1024 + n0 + n];
            }
        }
        __syncthreads();
        #pragma unroll
        for (int k = 0; k < 16; ++k) {
            float4 av = *(const float4*)&As[k][ty * 4];
            float4 bv = *(const float4*)&Bs[k][tx * 4];
            float a[4] = {av.x, av.y, av.z, av.w};
            float b[4] = {bv.x, bv.y, bv.z, bv.w};
            #pragma unroll
            for (int r = 0; r < 4; ++r)
                #pragma unroll
                for (int c = 0; c < 4; ++c)
                    acc[r][c] = fmaf(a[r], b[c], acc[r][c]);
        }
        __syncthreads();
    }

    float po[4][2] = {{0.f, 0.f}, {0.f, 0.f}, {0.f, 0.f}, {0.f, 0.f}};
    #pragma unroll
    for (int r = 0; r < 4; ++r) {
        int lr = ty * 4 + r;
        int qi = qis[lr], ri = ris[lr];
        float dv = ds[lr];
        #pragma unroll
        for (int c = 0; c < 4; ++c) {
            int n = n0 + tx * 4 + c;
            float h = acc[r][c]
                    + A[(size_t)qi * 1024 + n]
                    + Bv[(size_t)ri * 1024 + n]
                    + dv * w1[(size_t)1024 * 1024 + n]
                    + b1[n];
            h = fmaxf(h, 0.f);
            po[r][0] += h * w2[n * 2 + 0];
            po[r][1] += h * w2[n * 2 + 1];
        }
    }
    #pragma unroll
    for (int r = 0; r < 4; ++r) {
        red[tid][r][0] = po[r][0];
        red[tid][r][1] = po[r][1];
    }
    __syncthreads();
    if (tid < 128) {
        int ty2 = tid >> 3;          // 0..15
        int rr  = (tid >> 1) & 3;    // 0..3
        int cc  = tid & 1;           // 0..1
        float s = 0.f;
        #pragma unroll
        for (int x = 0; x < 16; ++x) s += red[ty2 * 16 + x][rr][cc];
        int p = p0 + ty2 * 4 + rr;
        partial[((size_t)bn * 16384 + p) * 2 + cc] = s;
    }
}

__global__ void final_reduce(const float* __restrict__ partial,
                             const float* __restrict__ b2, float* __restrict__ out)
{
    int gidx = blockIdx.x * 256 + threadIdx.x;   // 0..32767
    int p = gidx >> 1, c = gidx & 1;
    float s = b2[c];
    #pragma unroll
    for (int nt = 0; nt < 16; ++nt)
        s += partial[((size_t)nt * 16384 + p) * 2 + c];
    out[gidx] = s;
}

extern "C" void kernel_launch(void* const* d_in, const int* in_sizes, int n_in,
                              void* d_out, int out_size, void* d_ws, size_t ws_size,
                              hipStream_t stream) {
    const int*   iq     = (const int*)d_in[0];
    const int*   ir     = (const int*)d_in[1];
    const int*   ql     = (const int*)d_in[2];
    const int*   rl     = (const int*)d_in[3];
    const int*   nqi    = (const int*)d_in[4];
    const int*   nri    = (const int*)d_in[5];
    const float* emb    = (const float*)d_in[6];
    const float* gate_k = (const float*)d_in[7];
    const float* gate_b = (const float*)d_in[8];
    const float* cand_k = (const float*)d_in[9];
    const float* cand_b = (const float*)d_in[10];
    const float* w1     = (const float*)d_in[11];
    const float* b1     = (const float*)d_in[12];
    const float* w2     = (const float*)d_in[13];
    const float* b2     = (const float*)d_in[14];
    float* out = (float*)d_out;
    float* ws  = (float*)d_ws;

    float* Q       = ws;                 // 128*1024
    float* R       = ws + 131072;        // 128*1024
    float* A       = ws + 262144;        // 128*1024
    float* Bv      = ws + 393216;        // 128*1024
    float* dist    = ws + 524288;        // 128*128
    float* partial = ws + 540672;        // 16*16384*2

    gru_encode<<<128, 1024, 0, stream>>>(iq, ir, ql, rl, emb, gate_k, gate_b,
                                         cand_k, cand_b, Q, R);
    dist_kernel<<<64, 256, 0, stream>>>(Q, R, dist);
    ab_kernel<<<dim3(4, 8, 2), 256, 0, stream>>>(Q, R, w1, A, Bv);
    pair_gemm<<<dim3(256, 16), 256, 0, stream>>>(Q, R, A, Bv, dist, nqi, nri,
                                                 w1, b1, w2, partial);
    final_reduce<<<128, 256, 0, stream>>>(partial, b2, out);
}

// Round 3
// 2710.040 us; speedup vs baseline: 2.0676x; 1.1178x over previous
//
#include <hip/hip_runtime.h>
#include <cmath>

__device__ __forceinline__ float sigm(float x) { return 1.0f / (1.0f + expf(-x)); }

// ---- GRU hot loops -------------------------------------------------------
// gate: thread (cg = tid&127 -> cols 4cg..4cg+3, q = tid>>7 -> k in [64q,64q+64))
// Accumulates A[r] = sum_k in0t[k][r] * gk[k][c0..c0+3]  (float4 weight loads,
// one broadcast ds_read_b128 for the 4 batch rows).
__device__ __forceinline__ void gate_partial(
    const float (*in0t)[4], float* pbuf, const float* __restrict__ gk, int tid)
{
    int cg = tid & 127, q = tid >> 7;
    int c0 = cg * 4;
    const float* gp = gk + (size_t)(q * 64) * 512 + c0;
    const float4* xp = (const float4*)in0t[q * 64];
    float4 A0 = {0.f,0.f,0.f,0.f}, A1 = {0.f,0.f,0.f,0.f};
    float4 A2 = {0.f,0.f,0.f,0.f}, A3 = {0.f,0.f,0.f,0.f};
    #pragma unroll 8
    for (int i = 0; i < 64; ++i) {
        const float4 w = *(const float4*)(gp + (size_t)i * 512);
        const float4 x = xp[i];
        A0.x = fmaf(x.x, w.x, A0.x); A0.y = fmaf(x.x, w.y, A0.y);
        A0.z = fmaf(x.x, w.z, A0.z); A0.w = fmaf(x.x, w.w, A0.w);
        A1.x = fmaf(x.y, w.x, A1.x); A1.y = fmaf(x.y, w.y, A1.y);
        A1.z = fmaf(x.y, w.z, A1.z); A1.w = fmaf(x.y, w.w, A1.w);
        A2.x = fmaf(x.z, w.x, A2.x); A2.y = fmaf(x.z, w.y, A2.y);
        A2.z = fmaf(x.z, w.z, A2.z); A2.w = fmaf(x.z, w.w, A2.w);
        A3.x = fmaf(x.w, w.x, A3.x); A3.y = fmaf(x.w, w.y, A3.y);
        A3.z = fmaf(x.w, w.z, A3.z); A3.w = fmaf(x.w, w.w, A3.w);
    }
    *(float4*)&pbuf[(q * 4 + 0) * 512 + c0] = A0;
    *(float4*)&pbuf[(q * 4 + 1) * 512 + c0] = A1;
    *(float4*)&pbuf[(q * 4 + 2) * 512 + c0] = A2;
    *(float4*)&pbuf[(q * 4 + 3) * 512 + c0] = A3;
}

// cand: thread (cg = tid&63 -> cols 4cg..4cg+3, q = tid>>6 -> k in [32q,32q+32))
__device__ __forceinline__ void cand_partial(
    const float (*in0t)[4], float* pbuf, const float* __restrict__ ck, int tid)
{
    int cg = tid & 63, q = tid >> 6;
    int c0 = cg * 4;
    const float* cp = ck + (size_t)(q * 32) * 256 + c0;
    const float4* xp = (const float4*)in0t[q * 32];
    float4 A0 = {0.f,0.f,0.f,0.f}, A1 = {0.f,0.f,0.f,0.f};
    float4 A2 = {0.f,0.f,0.f,0.f}, A3 = {0.f,0.f,0.f,0.f};
    #pragma unroll 8
    for (int i = 0; i < 32; ++i) {
        const float4 w = *(const float4*)(cp + (size_t)i * 256);
        const float4 x = xp[i];
        A0.x = fmaf(x.x, w.x, A0.x); A0.y = fmaf(x.x, w.y, A0.y);
        A0.z = fmaf(x.x, w.z, A0.z); A0.w = fmaf(x.x, w.w, A0.w);
        A1.x = fmaf(x.y, w.x, A1.x); A1.y = fmaf(x.y, w.y, A1.y);
        A1.z = fmaf(x.y, w.z, A1.z); A1.w = fmaf(x.y, w.w, A1.w);
        A2.x = fmaf(x.z, w.x, A2.x); A2.y = fmaf(x.z, w.y, A2.y);
        A2.z = fmaf(x.z, w.z, A2.z); A2.w = fmaf(x.z, w.w, A2.w);
        A3.x = fmaf(x.w, w.x, A3.x); A3.y = fmaf(x.w, w.y, A3.y);
        A3.z = fmaf(x.w, w.z, A3.z); A3.w = fmaf(x.w, w.w, A3.w);
    }
    *(float4*)&pbuf[(q * 4 + 0) * 256 + c0] = A0;
    *(float4*)&pbuf[(q * 4 + 1) * 256 + c0] = A1;
    *(float4*)&pbuf[(q * 4 + 2) * 256 + c0] = A2;
    *(float4*)&pbuf[(q * 4 + 3) * 256 + c0] = A3;
}

// grid = 128 blocks x 1024 threads; block = (encoder, 4-row chunk), fully
// workgroup-local recurrence. XCD swizzle: 2 XCDs per encoder -> each XCD L2
// holds one encoder's 3 MB weight set.
__global__ __launch_bounds__(1024, 4) void gru_encode(
    const int* __restrict__ iq, const int* __restrict__ ir,
    const int* __restrict__ ql, const int* __restrict__ rl,
    const float* __restrict__ emb,
    const float* __restrict__ gate_k, const float* __restrict__ gate_b,
    const float* __restrict__ cand_k, const float* __restrict__ cand_b,
    float* __restrict__ Qo, float* __restrict__ Ro)
{
    int bid = blockIdx.x;
    int xcd = bid & 7;
    int enc = xcd >> 1;
    int chunk = (xcd & 1) * 16 + (bid >> 3);
    int b0 = chunk * 4;
    int tid = threadIdx.x;
    int c = tid & 255, r = tid >> 8;   // reduce/fill mapping

    const int* toks = (enc < 2) ? iq : ir;
    const int* lens = (enc < 2) ? ql : rl;
    const bool bw = (enc & 1);

    const float* gk1 = gate_k + (size_t)(enc * 2 + 0) * 512 * 512;
    const float* gk2 = gate_k + (size_t)(enc * 2 + 1) * 512 * 512;
    const float* gb1 = gate_b + (enc * 2 + 0) * 512;
    const float* gb2 = gate_b + (enc * 2 + 1) * 512;
    const float* ck1 = cand_k + (size_t)(enc * 2 + 0) * 512 * 256;
    const float* ck2 = cand_k + (size_t)(enc * 2 + 1) * 512 * 256;
    const float* cb1 = cand_b + (enc * 2 + 0) * 256;
    const float* cb2 = cand_b + (enc * 2 + 1) * 256;

    __shared__ float in0t[512][4];    // [k][batch row]
    __shared__ float pbuf[16384];     // gate view [8][4][512] / cand view [16][4][256]
    __shared__ float h1t[256][4];
    __shared__ float h2t[256][4];
    __shared__ float gzt[256][4];
    __shared__ int tok_s[4];
    __shared__ int len_s[4];

    h1t[c][r] = 0.f;
    h2t[c][r] = 0.f;
    if (tid < 4) len_s[tid] = lens[b0 + tid];
    __syncthreads();
    int maxlen = max(max(len_s[0], len_s[1]), max(len_s[2], len_s[3]));
    if (tid < 4) {
        int len = len_s[tid];
        tok_s[tid] = toks[(b0 + tid) * 64 + (bw ? (len - 1) : 0)];
    }
    __syncthreads();

    for (int t = 0; t < maxlen; ++t) {
        // FILL: in0t = [x_t ; h1]
        in0t[c][r]       = emb[(size_t)tok_s[r] * 256 + c];
        in0t[256 + c][r] = h1t[c][r];
        __syncthreads();

        // ---- layer 1 ----
        gate_partial(in0t, pbuf, gk1, tid);
        __syncthreads();
        {   // reduce: r-gate -> in0t[256+c] = rv*h1 ; z-gate -> gzt
            float s0 = gb1[c], s1 = gb1[256 + c];
            #pragma unroll
            for (int q = 0; q < 8; ++q) {
                s0 += pbuf[(q * 4 + r) * 512 + c];
                s1 += pbuf[(q * 4 + r) * 512 + c + 256];
            }
            in0t[256 + c][r] = sigm(s0) * h1t[c][r];
            gzt[c][r] = sigm(s1);
        }
        __syncthreads();
        cand_partial(in0t, pbuf, ck1, tid);
        __syncthreads();
        {   // reduce + h1 update; stage [h1n ; h2] for layer 2
            float s = cb1[c];
            #pragma unroll
            for (int q = 0; q < 16; ++q) s += pbuf[(q * 4 + r) * 256 + c];
            float cv = tanhf(s);
            float z = gzt[c][r];
            float hn = fmaf(z, h1t[c][r] - cv, cv);
            if (t < len_s[r]) h1t[c][r] = hn;
            in0t[c][r]       = hn;          // layer-2 x (unmasked, matches ref)
            in0t[256 + c][r] = h2t[c][r];   // layer-2 h
        }
        __syncthreads();

        // ---- layer 2 ----
        gate_partial(in0t, pbuf, gk2, tid);
        __syncthreads();
        {
            float s0 = gb2[c], s1 = gb2[256 + c];
            #pragma unroll
            for (int q = 0; q < 8; ++q) {
                s0 += pbuf[(q * 4 + r) * 512 + c];
                s1 += pbuf[(q * 4 + r) * 512 + c + 256];
            }
            in0t[256 + c][r] = sigm(s0) * h2t[c][r];
            gzt[c][r] = sigm(s1);
        }
        __syncthreads();
        cand_partial(in0t, pbuf, ck2, tid);
        __syncthreads();
        {
            float s = cb2[c];
            #pragma unroll
            for (int q = 0; q < 16; ++q) s += pbuf[(q * 4 + r) * 256 + c];
            float cv = tanhf(s);
            float z = gzt[c][r];
            float hn = fmaf(z, h2t[c][r] - cv, cv);
            if (t < len_s[r]) h2t[c][r] = hn;
        }
        if (tid < 4) {   // token prefetch for t+1
            int t2 = t + 1;
            if (t2 < 64) {
                int len = len_s[tid];
                int tt = bw ? ((t2 < len) ? (len - 1 - t2) : t2) : t2;
                tok_s[tid] = toks[(b0 + tid) * 64 + tt];
            }
        }
        __syncthreads();
    }

    float* outp = (enc < 2) ? Qo : Ro;
    int off = (enc & 1) ? 512 : 0;
    outp[(size_t)(b0 + r) * 1024 + off + c]       = h1t[c][r];
    outp[(size_t)(b0 + r) * 1024 + off + 256 + c] = h2t[c][r];
}

// dist[i][j] = dot(Q[i], R[j]); 16384 threads, one pair each.
__global__ void dist_kernel(const float* __restrict__ Q, const float* __restrict__ R,
                            float* __restrict__ dist)
{
    int gidx = blockIdx.x * 256 + threadIdx.x;
    int i = gidx >> 7, j = gidx & 127;
    const float4* q4 = (const float4*)(Q + (size_t)i * 1024);
    const float4* r4 = (const float4*)(R + (size_t)j * 1024);
    float acc = 0.f;
    for (int k = 0; k < 256; ++k) {
        float4 a = q4[k], b = r4[k];
        acc += a.x * b.x + a.y * b.y + a.z * b.z + a.w * b.w;
    }
    dist[gidx] = acc;
}

// A = Q @ (Wq + Wdiff), Bv = R @ (Wr - Wdiff)
__global__ __launch_bounds__(256) void ab_kernel(
    const float* __restrict__ Q, const float* __restrict__ R,
    const float* __restrict__ w1, float* __restrict__ A, float* __restrict__ Bv)
{
    int nb = blockIdx.x, rb = blockIdx.y, mat = blockIdx.z;
    int tid = threadIdx.x;
    int n = nb * 256 + tid;
    int r0 = rb * 16;
    const float* src   = mat ? R : Q;
    const float* wmain = mat ? (w1 + (size_t)3073 * 1024) : w1;
    const float* wdiff = w1 + (size_t)1025 * 1024;
    float sgn = mat ? -1.f : 1.f;

    __shared__ float Qs[16][64];
    float acc[16];
    #pragma unroll
    for (int r = 0; r < 16; ++r) acc[r] = 0.f;

    for (int k0 = 0; k0 < 1024; k0 += 64) {
        __syncthreads();
        #pragma unroll
        for (int s = 0; s < 4; ++s) {
            int e = s * 256 + tid;
            int r = e >> 6, kk = e & 63;
            Qs[r][kk] = src[(size_t)(r0 + r) * 1024 + k0 + kk];
        }
        __syncthreads();
        for (int kk = 0; kk < 64; ++kk) {
            size_t row = (size_t)(k0 + kk) * 1024 + n;
            float w = wmain[row] + sgn * wdiff[row];
            #pragma unroll
            for (int r = 0; r < 16; ++r)
                acc[r] = fmaf(Qs[r][kk], w, acc[r]);
        }
    }
    float* dst = mat ? Bv : A;
    #pragma unroll
    for (int r = 0; r < 16; ++r)
        dst[(size_t)(r0 + r) * 1024 + n] = acc[r];
}

// C[p][n] = sum_k Q[qi[p]][k]*R[ri[p]][k]*Wprod[k][n]; fused epilogue -> per-N-tile w2 partials
__global__ __launch_bounds__(256) void pair_gemm(
    const float* __restrict__ Q, const float* __restrict__ R,
    const float* __restrict__ A, const float* __restrict__ Bv,
    const float* __restrict__ dist,
    const int* __restrict__ nqi, const int* __restrict__ nri,
    const float* __restrict__ w1, const float* __restrict__ b1,
    const float* __restrict__ w2, float* __restrict__ partial)
{
    int bm = blockIdx.x;
    int bn = blockIdx.y;
    int tid = threadIdx.x;
    int tx = tid & 15, ty = tid >> 4;
    int p0 = bm * 64, n0 = bn * 64;

    __shared__ __align__(16) float As[16][68];
    __shared__ __align__(16) float Bs[16][68];
    __shared__ int   qis[64];
    __shared__ int   ris[64];
    __shared__ float ds[64];
    __shared__ float red[256][4][2];

    if (tid < 64) {
        int p = p0 + tid;
        int qi, ri;
        if (p < 128) { qi = p; ri = p; }
        else         { qi = nqi[p - 128]; ri = nri[p - 128]; }
        qis[tid] = qi; ris[tid] = ri; ds[tid] = dist[qi * 128 + ri];
    }
    __syncthreads();

    float acc[4][4];
    #pragma unroll
    for (int r = 0; r < 4; ++r)
        #pragma unroll
        for (int c = 0; c < 4; ++c) acc[r][c] = 0.f;

    int lrow = tid >> 2;
    int kq   = tid & 3;
    const float* wp = w1 + (size_t)2049 * 1024;

    for (int kt = 0; kt < 64; ++kt) {
        int kbase = kt * 16;
        {
            const float4 q4 = *(const float4*)(Q + (size_t)qis[lrow] * 1024 + kbase + kq * 4);
            const float4 r4 = *(const float4*)(R + (size_t)ris[lrow] * 1024 + kbase + kq * 4);
            As[kq * 4 + 0][lrow] = q4.x * r4.x;
            As[kq * 4 + 1][lrow] = q4.y * r4.y;
            As[kq * 4 + 2][lrow] = q4.z * r4.z;
            As[kq * 4 + 3][lrow] = q4.w * r4.w;
        }
        {
            int n = tid & 63, kr = tid >> 6;
            #pragma unroll
            for (int s = 0; s < 4; ++s) {
                int k = kr * 4 + s;
                Bs[k][n] = wp[(size_t)(kbase + k) * 1024 + n0 + n];
            }
        }
        __syncthreads();
        #pragma unroll
        for (int k = 0; k < 16; ++k) {
            float4 av = *(const float4*)&As[k][ty * 4];
            float4 bv = *(const float4*)&Bs[k][tx * 4];
            float a[4] = {av.x, av.y, av.z, av.w};
            float b[4] = {bv.x, bv.y, bv.z, bv.w};
            #pragma unroll
            for (int r = 0; r < 4; ++r)
                #pragma unroll
                for (int c = 0; c < 4; ++c)
                    acc[r][c] = fmaf(a[r], b[c], acc[r][c]);
        }
        __syncthreads();
    }

    float po[4][2] = {{0.f, 0.f}, {0.f, 0.f}, {0.f, 0.f}, {0.f, 0.f}};
    #pragma unroll
    for (int r = 0; r < 4; ++r) {
        int lr = ty * 4 + r;
        int qi = qis[lr], ri = ris[lr];
        float dv = ds[lr];
        #pragma unroll
        for (int c = 0; c < 4; ++c) {
            int n = n0 + tx * 4 + c;
            float h = acc[r][c]
                    + A[(size_t)qi * 1024 + n]
                    + Bv[(size_t)ri * 1024 + n]
                    + dv * w1[(size_t)1024 * 1024 + n]
                    + b1[n];
            h = fmaxf(h, 0.f);
            po[r][0] += h * w2[n * 2 + 0];
            po[r][1] += h * w2[n * 2 + 1];
        }
    }
    #pragma unroll
    for (int r = 0; r < 4; ++r) {
        red[tid][r][0] = po[r][0];
        red[tid][r][1] = po[r][1];
    }
    __syncthreads();
    if (tid < 128) {
        int ty2 = tid >> 3;
        int rr  = (tid >> 1) & 3;
        int cc  = tid & 1;
        float s = 0.f;
        #pragma unroll
        for (int x = 0; x < 16; ++x) s += red[ty2 * 16 + x][rr][cc];
        int p = p0 + ty2 * 4 + rr;
        partial[((size_t)bn * 16384 + p) * 2 + cc] = s;
    }
}

__global__ void final_reduce(const float* __restrict__ partial,
                             const float* __restrict__ b2, float* __restrict__ out)
{
    int gidx = blockIdx.x * 256 + threadIdx.x;
    int p = gidx >> 1, c = gidx & 1;
    float s = b2[c];
    #pragma unroll
    for (int nt = 0; nt < 16; ++nt)
        s += partial[((size_t)nt * 16384 + p) * 2 + c];
    out[gidx] = s;
}

extern "C" void kernel_launch(void* const* d_in, const int* in_sizes, int n_in,
                              void* d_out, int out_size, void* d_ws, size_t ws_size,
                              hipStream_t stream) {
    const int*   iq     = (const int*)d_in[0];
    const int*   ir     = (const int*)d_in[1];
    const int*   ql     = (const int*)d_in[2];
    const int*   rl     = (const int*)d_in[3];
    const int*   nqi    = (const int*)d_in[4];
    const int*   nri    = (const int*)d_in[5];
    const float* emb    = (const float*)d_in[6];
    const float* gate_k = (const float*)d_in[7];
    const float* gate_b = (const float*)d_in[8];
    const float* cand_k = (const float*)d_in[9];
    const float* cand_b = (const float*)d_in[10];
    const float* w1     = (const float*)d_in[11];
    const float* b1     = (const float*)d_in[12];
    const float* w2     = (const float*)d_in[13];
    const float* b2     = (const float*)d_in[14];
    float* out = (float*)d_out;
    float* ws  = (float*)d_ws;

    float* Q       = ws;                 // 128*1024
    float* R       = ws + 131072;        // 128*1024
    float* A       = ws + 262144;        // 128*1024
    float* Bv      = ws + 393216;        // 128*1024
    float* dist    = ws + 524288;        // 128*128
    float* partial = ws + 540672;        // 16*16384*2

    gru_encode<<<128, 1024, 0, stream>>>(iq, ir, ql, rl, emb, gate_k, gate_b,
                                         cand_k, cand_b, Q, R);
    dist_kernel<<<64, 256, 0, stream>>>(Q, R, dist);
    ab_kernel<<<dim3(4, 8, 2), 256, 0, stream>>>(Q, R, w1, A, Bv);
    pair_gemm<<<dim3(256, 16), 256, 0, stream>>>(Q, R, A, Bv, dist, nqi, nri,
                                                 w1, b1, w2, partial);
    final_reduce<<<128, 256, 0, stream>>>(partial, b2, out);
}

// Round 4
// 2042.940 us; speedup vs baseline: 2.7427x; 1.3265x over previous
//
#include <hip/hip_runtime.h>
#include <hip/hip_fp16.h>
#include <cmath>

typedef _Float16 h2 __attribute__((ext_vector_type(2)));

#if defined(__has_builtin)
#if __has_builtin(__builtin_amdgcn_fdot2)
#define HAS_FDOT2 1
#endif
#endif

__device__ __forceinline__ float fdot2f(h2 a, h2 b, float c) {
#ifdef HAS_FDOT2
    return __builtin_amdgcn_fdot2(a, b, c, false);
#else
    c = fmaf((float)a[0], (float)b[0], c);
    return fmaf((float)a[1], (float)b[1], c);
#endif
}

__device__ __forceinline__ float sigm(float x) { return 1.0f / (1.0f + expf(-x)); }

// ---- weight conversion: fp32 -> k-pair-packed f16 ------------------------
// gkh[e2][kp][col] = h2(gk[e2][2kp][col], gk[e2][2kp+1][col])   col in [0,512)
// ckh[e2][kp][col] = h2(ck[e2][2kp][col], ck[e2][2kp+1][col])   col in [0,256)
__global__ __launch_bounds__(256) void convert_weights(
    const float* __restrict__ gate_k, const float* __restrict__ cand_k,
    float* __restrict__ gkh, float* __restrict__ ckh)
{
    int i = blockIdx.x * 256 + threadIdx.x;
    if (i < 8 * 256 * 512) {
        int col = i & 511, kp = (i >> 9) & 255, e2 = i >> 17;
        const float* src = gate_k + ((size_t)e2 * 512 + 2 * kp) * 512 + col;
        h2 v; v[0] = (_Float16)src[0]; v[1] = (_Float16)src[512];
        gkh[i] = __builtin_bit_cast(float, v);
    }
    if (i < 8 * 256 * 256) {
        int col = i & 255, kp = (i >> 8) & 255, e2 = i >> 16;
        const float* src = cand_k + ((size_t)e2 * 512 + 2 * kp) * 256 + col;
        h2 v; v[0] = (_Float16)src[0]; v[1] = (_Float16)src[256];
        ckh[i] = __builtin_bit_cast(float, v);
    }
}

// ---- GRU hot loops (f16 dot2) -------------------------------------------
// in0f layout: f16 element (k, row) at  (k>>1)*8 + row*2 + (k&1)
// -> one 16B read at kp*16 yields rows 0..3 k-pairs (broadcast across wave).
__device__ __forceinline__ void gate_partial_h(
    const _Float16* in0f, float* pbuf, const float* __restrict__ gk, int tid)
{
    int cg = tid & 127, q = tid >> 7;
    int c0 = cg * 4;
    const float* gp = gk + (size_t)(q * 32) * 512 + c0;
    const _Float16* xp = in0f + q * 32 * 8;
    float4 A0 = {0.f,0.f,0.f,0.f}, A1 = {0.f,0.f,0.f,0.f};
    float4 A2 = {0.f,0.f,0.f,0.f}, A3 = {0.f,0.f,0.f,0.f};
    #pragma unroll 8
    for (int i = 0; i < 32; ++i) {
        float4 wf = *(const float4*)(gp + (size_t)i * 512);
        float4 xf = *(const float4*)(xp + i * 8);
        h2 w0 = __builtin_bit_cast(h2, wf.x), w1 = __builtin_bit_cast(h2, wf.y);
        h2 w2 = __builtin_bit_cast(h2, wf.z), w3 = __builtin_bit_cast(h2, wf.w);
        h2 x0 = __builtin_bit_cast(h2, xf.x), x1 = __builtin_bit_cast(h2, xf.y);
        h2 x2 = __builtin_bit_cast(h2, xf.z), x3 = __builtin_bit_cast(h2, xf.w);
        A0.x = fdot2f(x0, w0, A0.x); A0.y = fdot2f(x0, w1, A0.y);
        A0.z = fdot2f(x0, w2, A0.z); A0.w = fdot2f(x0, w3, A0.w);
        A1.x = fdot2f(x1, w0, A1.x); A1.y = fdot2f(x1, w1, A1.y);
        A1.z = fdot2f(x1, w2, A1.z); A1.w = fdot2f(x1, w3, A1.w);
        A2.x = fdot2f(x2, w0, A2.x); A2.y = fdot2f(x2, w1, A2.y);
        A2.z = fdot2f(x2, w2, A2.z); A2.w = fdot2f(x2, w3, A2.w);
        A3.x = fdot2f(x3, w0, A3.x); A3.y = fdot2f(x3, w1, A3.y);
        A3.z = fdot2f(x3, w2, A3.z); A3.w = fdot2f(x3, w3, A3.w);
    }
    *(float4*)&pbuf[(q * 4 + 0) * 512 + c0] = A0;
    *(float4*)&pbuf[(q * 4 + 1) * 512 + c0] = A1;
    *(float4*)&pbuf[(q * 4 + 2) * 512 + c0] = A2;
    *(float4*)&pbuf[(q * 4 + 3) * 512 + c0] = A3;
}

__device__ __forceinline__ void cand_partial_h(
    const _Float16* in0f, float* pbuf, const float* __restrict__ ck, int tid)
{
    int cg = tid & 63, q = tid >> 6;
    int c0 = cg * 4;
    const float* cp = ck + (size_t)(q * 16) * 256 + c0;
    const _Float16* xp = in0f + q * 16 * 8;
    float4 A0 = {0.f,0.f,0.f,0.f}, A1 = {0.f,0.f,0.f,0.f};
    float4 A2 = {0.f,0.f,0.f,0.f}, A3 = {0.f,0.f,0.f,0.f};
    #pragma unroll 8
    for (int i = 0; i < 16; ++i) {
        float4 wf = *(const float4*)(cp + (size_t)i * 256);
        float4 xf = *(const float4*)(xp + i * 8);
        h2 w0 = __builtin_bit_cast(h2, wf.x), w1 = __builtin_bit_cast(h2, wf.y);
        h2 w2 = __builtin_bit_cast(h2, wf.z), w3 = __builtin_bit_cast(h2, wf.w);
        h2 x0 = __builtin_bit_cast(h2, xf.x), x1 = __builtin_bit_cast(h2, xf.y);
        h2 x2 = __builtin_bit_cast(h2, xf.z), x3 = __builtin_bit_cast(h2, xf.w);
        A0.x = fdot2f(x0, w0, A0.x); A0.y = fdot2f(x0, w1, A0.y);
        A0.z = fdot2f(x0, w2, A0.z); A0.w = fdot2f(x0, w3, A0.w);
        A1.x = fdot2f(x1, w0, A1.x); A1.y = fdot2f(x1, w1, A1.y);
        A1.z = fdot2f(x1, w2, A1.z); A1.w = fdot2f(x1, w3, A1.w);
        A2.x = fdot2f(x2, w0, A2.x); A2.y = fdot2f(x2, w1, A2.y);
        A2.z = fdot2f(x2, w2, A2.z); A2.w = fdot2f(x2, w3, A2.w);
        A3.x = fdot2f(x3, w0, A3.x); A3.y = fdot2f(x3, w1, A3.y);
        A3.z = fdot2f(x3, w2, A3.z); A3.w = fdot2f(x3, w3, A3.w);
    }
    *(float4*)&pbuf[(q * 4 + 0) * 256 + c0] = A0;
    *(float4*)&pbuf[(q * 4 + 1) * 256 + c0] = A1;
    *(float4*)&pbuf[(q * 4 + 2) * 256 + c0] = A2;
    *(float4*)&pbuf[(q * 4 + 3) * 256 + c0] = A3;
}

// grid = 128 blocks x 1024 threads; block = (encoder, 4-row chunk), fully
// workgroup-local recurrence; f16 weights, fp32 h state/partials.
__global__ __launch_bounds__(1024, 4) void gru_encode(
    const int* __restrict__ iq, const int* __restrict__ ir,
    const int* __restrict__ ql, const int* __restrict__ rl,
    const float* __restrict__ emb,
    const float* __restrict__ gkh, const float* __restrict__ gate_b,
    const float* __restrict__ ckh, const float* __restrict__ cand_b,
    float* __restrict__ Qo, float* __restrict__ Ro)
{
    int bid = blockIdx.x;
    int xcd = bid & 7;
    int enc = xcd >> 1;
    int chunk = (xcd & 1) * 16 + (bid >> 3);
    int b0 = chunk * 4;
    int tid = threadIdx.x;
    int c = tid & 255, r = tid >> 8;

    const int* toks = (enc < 2) ? iq : ir;
    const int* lens = (enc < 2) ? ql : rl;
    const bool bw = (enc & 1);

    const float* gk1 = gkh + (size_t)(enc * 2 + 0) * 131072;
    const float* gk2 = gkh + (size_t)(enc * 2 + 1) * 131072;
    const float* gb1 = gate_b + (enc * 2 + 0) * 512;
    const float* gb2 = gate_b + (enc * 2 + 1) * 512;
    const float* ck1 = ckh + (size_t)(enc * 2 + 0) * 65536;
    const float* ck2 = ckh + (size_t)(enc * 2 + 1) * 65536;
    const float* cb1 = cand_b + (enc * 2 + 0) * 256;
    const float* cb2 = cand_b + (enc * 2 + 1) * 256;

    __shared__ __align__(16) _Float16 in0f[256 * 8];   // 4KB  [kp][row*2+(k&1)]
    __shared__ float pbuf[16384];                      // 64KB partials
    __shared__ float h1rt[4][256];
    __shared__ float h2rt[4][256];
    __shared__ float gzt[4][256];
    __shared__ int tok_s[4];
    __shared__ int len_s[4];

    h1rt[r][c] = 0.f;
    h2rt[r][c] = 0.f;
    if (tid < 4) len_s[tid] = lens[b0 + tid];
    __syncthreads();
    int maxlen = max(max(len_s[0], len_s[1]), max(len_s[2], len_s[3]));
    if (tid < 4) {
        int len = len_s[tid];
        tok_s[tid] = toks[(b0 + tid) * 64 + (bw ? (len - 1) : 0)];
    }
    __syncthreads();

    for (int t = 0; t < maxlen; ++t) {
        // FILL: in0f = [x_t ; h1] as f16 pairs (pair-per-thread, b32 writes)
        if (tid < 512) {
            int kp = tid >> 2, rr = tid & 3;
            float2 xv = *(const float2*)(emb + (size_t)tok_s[rr] * 256 + 2 * kp);
            h2 v; v[0] = (_Float16)xv.x; v[1] = (_Float16)xv.y;
            *(float*)(in0f + kp * 8 + rr * 2) = __builtin_bit_cast(float, v);
        } else {
            int m = (tid - 512) >> 2, rr = tid & 3;
            h2 v; v[0] = (_Float16)h1rt[rr][2 * m]; v[1] = (_Float16)h1rt[rr][2 * m + 1];
            *(float*)(in0f + (128 + m) * 8 + rr * 2) = __builtin_bit_cast(float, v);
        }
        __syncthreads();

        // ---- layer 1 ----
        gate_partial_h(in0f, pbuf, gk1, tid);
        __syncthreads();
        {   // reduce: r-gate -> in0f[k=256+c] = f16(rv*h1) ; z-gate -> gzt
            float s0 = gb1[c], s1 = gb1[256 + c];
            #pragma unroll
            for (int q = 0; q < 8; ++q) {
                s0 += pbuf[(q * 4 + r) * 512 + c];
                s1 += pbuf[(q * 4 + r) * 512 + c + 256];
            }
            float rh = sigm(s0) * h1rt[r][c];
            gzt[r][c] = sigm(s1);
            in0f[((256 + c) >> 1) * 8 + r * 2 + (c & 1)] = (_Float16)rh;
        }
        __syncthreads();
        cand_partial_h(in0f, pbuf, ck1, tid);
        __syncthreads();
        {   // reduce + h1 update; stage [h1n ; h2] for layer 2
            float s = cb1[c];
            #pragma unroll
            for (int q = 0; q < 16; ++q) s += pbuf[(q * 4 + r) * 256 + c];
            float cv = tanhf(s);
            float z = gzt[r][c];
            float hn = fmaf(z, h1rt[r][c] - cv, cv);
            if (t < len_s[r]) h1rt[r][c] = hn;
            in0f[(c >> 1) * 8 + r * 2 + (c & 1)]         = (_Float16)hn;
            in0f[((256 + c) >> 1) * 8 + r * 2 + (c & 1)] = (_Float16)h2rt[r][c];
        }
        __syncthreads();

        // ---- layer 2 ----
        gate_partial_h(in0f, pbuf, gk2, tid);
        __syncthreads();
        {
            float s0 = gb2[c], s1 = gb2[256 + c];
            #pragma unroll
            for (int q = 0; q < 8; ++q) {
                s0 += pbuf[(q * 4 + r) * 512 + c];
                s1 += pbuf[(q * 4 + r) * 512 + c + 256];
            }
            float rh = sigm(s0) * h2rt[r][c];
            gzt[r][c] = sigm(s1);
            in0f[((256 + c) >> 1) * 8 + r * 2 + (c & 1)] = (_Float16)rh;
        }
        __syncthreads();
        cand_partial_h(in0f, pbuf, ck2, tid);
        __syncthreads();
        {
            float s = cb2[c];
            #pragma unroll
            for (int q = 0; q < 16; ++q) s += pbuf[(q * 4 + r) * 256 + c];
            float cv = tanhf(s);
            float z = gzt[r][c];
            float hn = fmaf(z, h2rt[r][c] - cv, cv);
            if (t < len_s[r]) h2rt[r][c] = hn;
        }
        if (tid < 4) {   // token prefetch for t+1
            int t2 = t + 1;
            if (t2 < 64) {
                int len = len_s[tid];
                int tt = bw ? ((t2 < len) ? (len - 1 - t2) : t2) : t2;
                tok_s[tid] = toks[(b0 + tid) * 64 + tt];
            }
        }
        __syncthreads();
    }

    float* outp = (enc < 2) ? Qo : Ro;
    int off = (enc & 1) ? 512 : 0;
    outp[(size_t)(b0 + r) * 1024 + off + c]       = h1rt[r][c];
    outp[(size_t)(b0 + r) * 1024 + off + 256 + c] = h2rt[r][c];
}

// dist[i][j] = dot(Q[i], R[j]); 16384 threads, one pair each.
__global__ void dist_kernel(const float* __restrict__ Q, const float* __restrict__ R,
                            float* __restrict__ dist)
{
    int gidx = blockIdx.x * 256 + threadIdx.x;
    int i = gidx >> 7, j = gidx & 127;
    const float4* q4 = (const float4*)(Q + (size_t)i * 1024);
    const float4* r4 = (const float4*)(R + (size_t)j * 1024);
    float acc = 0.f;
    for (int k = 0; k < 256; ++k) {
        float4 a = q4[k], b = r4[k];
        acc += a.x * b.x + a.y * b.y + a.z * b.z + a.w * b.w;
    }
    dist[gidx] = acc;
}

// A = Q @ (Wq + Wdiff), Bv = R @ (Wr - Wdiff)
__global__ __launch_bounds__(256) void ab_kernel(
    const float* __restrict__ Q, const float* __restrict__ R,
    const float* __restrict__ w1, float* __restrict__ A, float* __restrict__ Bv)
{
    int nb = blockIdx.x, rb = blockIdx.y, mat = blockIdx.z;
    int tid = threadIdx.x;
    int n = nb * 256 + tid;
    int r0 = rb * 16;
    const float* src   = mat ? R : Q;
    const float* wmain = mat ? (w1 + (size_t)3073 * 1024) : w1;
    const float* wdiff = w1 + (size_t)1025 * 1024;
    float sgn = mat ? -1.f : 1.f;

    __shared__ float Qs[16][64];
    float acc[16];
    #pragma unroll
    for (int r = 0; r < 16; ++r) acc[r] = 0.f;

    for (int k0 = 0; k0 < 1024; k0 += 64) {
        __syncthreads();
        #pragma unroll
        for (int s = 0; s < 4; ++s) {
            int e = s * 256 + tid;
            int r = e >> 6, kk = e & 63;
            Qs[r][kk] = src[(size_t)(r0 + r) * 1024 + k0 + kk];
        }
        __syncthreads();
        for (int kk = 0; kk < 64; ++kk) {
            size_t row = (size_t)(k0 + kk) * 1024 + n;
            float w = wmain[row] + sgn * wdiff[row];
            #pragma unroll
            for (int r = 0; r < 16; ++r)
                acc[r] = fmaf(Qs[r][kk], w, acc[r]);
        }
    }
    float* dst = mat ? Bv : A;
    #pragma unroll
    for (int r = 0; r < 16; ++r)
        dst[(size_t)(r0 + r) * 1024 + n] = acc[r];
}

// C[p][n] = sum_k Q[qi[p]][k]*R[ri[p]][k]*Wprod[k][n]; fused epilogue -> per-N-tile w2 partials
__global__ __launch_bounds__(256) void pair_gemm(
    const float* __restrict__ Q, const float* __restrict__ R,
    const float* __restrict__ A, const float* __restrict__ Bv,
    const float* __restrict__ dist,
    const int* __restrict__ nqi, const int* __restrict__ nri,
    const float* __restrict__ w1, const float* __restrict__ b1,
    const float* __restrict__ w2, float* __restrict__ partial)
{
    int bm = blockIdx.x;
    int bn = blockIdx.y;
    int tid = threadIdx.x;
    int tx = tid & 15, ty = tid >> 4;
    int p0 = bm * 64, n0 = bn * 64;

    __shared__ __align__(16) float As[16][68];
    __shared__ __align__(16) float Bs[16][68];
    __shared__ int   qis[64];
    __shared__ int   ris[64];
    __shared__ float ds[64];
    __shared__ float red[256][4][2];

    if (tid < 64) {
        int p = p0 + tid;
        int qi, ri;
        if (p < 128) { qi = p; ri = p; }
        else         { qi = nqi[p - 128]; ri = nri[p - 128]; }
        qis[tid] = qi; ris[tid] = ri; ds[tid] = dist[qi * 128 + ri];
    }
    __syncthreads();

    float acc[4][4];
    #pragma unroll
    for (int r = 0; r < 4; ++r)
        #pragma unroll
        for (int c = 0; c < 4; ++c) acc[r][c] = 0.f;

    int lrow = tid >> 2;
    int kq   = tid & 3;
    const float* wp = w1 + (size_t)2049 * 1024;

    for (int kt = 0; kt < 64; ++kt) {
        int kbase = kt * 16;
        {
            const float4 q4 = *(const float4*)(Q + (size_t)qis[lrow] * 1024 + kbase + kq * 4);
            const float4 r4 = *(const float4*)(R + (size_t)ris[lrow] * 1024 + kbase + kq * 4);
            As[kq * 4 + 0][lrow] = q4.x * r4.x;
            As[kq * 4 + 1][lrow] = q4.y * r4.y;
            As[kq * 4 + 2][lrow] = q4.z * r4.z;
            As[kq * 4 + 3][lrow] = q4.w * r4.w;
        }
        {
            int n = tid & 63, kr = tid >> 6;
            #pragma unroll
            for (int s = 0; s < 4; ++s) {
                int k = kr * 4 + s;
                Bs[k][n] = wp[(size_t)(kbase + k) * 1024 + n0 + n];
            }
        }
        __syncthreads();
        #pragma unroll
        for (int k = 0; k < 16; ++k) {
            float4 av = *(const float4*)&As[k][ty * 4];
            float4 bv = *(const float4*)&Bs[k][tx * 4];
            float a[4] = {av.x, av.y, av.z, av.w};
            float b[4] = {bv.x, bv.y, bv.z, bv.w};
            #pragma unroll
            for (int r = 0; r < 4; ++r)
                #pragma unroll
                for (int c = 0; c < 4; ++c)
                    acc[r][c] = fmaf(a[r], b[c], acc[r][c]);
        }
        __syncthreads();
    }

    float po[4][2] = {{0.f, 0.f}, {0.f, 0.f}, {0.f, 0.f}, {0.f, 0.f}};
    #pragma unroll
    for (int r = 0; r < 4; ++r) {
        int lr = ty * 4 + r;
        int qi = qis[lr], ri = ris[lr];
        float dv = ds[lr];
        #pragma unroll
        for (int c = 0; c < 4; ++c) {
            int n = n0 + tx * 4 + c;
            float h = acc[r][c]
                    + A[(size_t)qi * 1024 + n]
                    + Bv[(size_t)ri * 1024 + n]
                    + dv * w1[(size_t)1024 * 1024 + n]
                    + b1[n];
            h = fmaxf(h, 0.f);
            po[r][0] += h * w2[n * 2 + 0];
            po[r][1] += h * w2[n * 2 + 1];
        }
    }
    #pragma unroll
    for (int r = 0; r < 4; ++r) {
        red[tid][r][0] = po[r][0];
        red[tid][r][1] = po[r][1];
    }
    __syncthreads();
    if (tid < 128) {
        int ty2 = tid >> 3;
        int rr  = (tid >> 1) & 3;
        int cc  = tid & 1;
        float s = 0.f;
        #pragma unroll
        for (int x = 0; x < 16; ++x) s += red[ty2 * 16 + x][rr][cc];
        int p = p0 + ty2 * 4 + rr;
        partial[((size_t)bn * 16384 + p) * 2 + cc] = s;
    }
}

__global__ void final_reduce(const float* __restrict__ partial,
                             const float* __restrict__ b2, float* __restrict__ out)
{
    int gidx = blockIdx.x * 256 + threadIdx.x;
    int p = gidx >> 1, c = gidx & 1;
    float s = b2[c];
    #pragma unroll
    for (int nt = 0; nt < 16; ++nt)
        s += partial[((size_t)nt * 16384 + p) * 2 + c];
    out[gidx] = s;
}

extern "C" void kernel_launch(void* const* d_in, const int* in_sizes, int n_in,
                              void* d_out, int out_size, void* d_ws, size_t ws_size,
                              hipStream_t stream) {
    const int*   iq     = (const int*)d_in[0];
    const int*   ir     = (const int*)d_in[1];
    const int*   ql     = (const int*)d_in[2];
    const int*   rl     = (const int*)d_in[3];
    const int*   nqi    = (const int*)d_in[4];
    const int*   nri    = (const int*)d_in[5];
    const float* emb    = (const float*)d_in[6];
    const float* gate_k = (const float*)d_in[7];
    const float* gate_b = (const float*)d_in[8];
    const float* cand_k = (const float*)d_in[9];
    const float* cand_b = (const float*)d_in[10];
    const float* w1     = (const float*)d_in[11];
    const float* b1     = (const float*)d_in[12];
    const float* w2     = (const float*)d_in[13];
    const float* b2     = (const float*)d_in[14];
    float* out = (float*)d_out;
    float* ws  = (float*)d_ws;

    float* Q       = ws;                 // 128*1024
    float* R       = ws + 131072;        // 128*1024
    float* A       = ws + 262144;        // 128*1024
    float* Bv      = ws + 393216;        // 128*1024
    float* dist    = ws + 524288;        // 128*128
    float* partial = ws + 540672;        // 16*16384*2
    float* gkh     = ws + 1064960;       // 8*256*512 h2 (as float units)
    float* ckh     = ws + 2113536;       // 8*256*256 h2
    // total ws use: 2,637,824 floats = 10.6 MB

    convert_weights<<<4096, 256, 0, stream>>>(gate_k, cand_k, gkh, ckh);
    gru_encode<<<128, 1024, 0, stream>>>(iq, ir, ql, rl, emb, gkh, gate_b,
                                         ckh, cand_b, Q, R);
    dist_kernel<<<64, 256, 0, stream>>>(Q, R, dist);
    ab_kernel<<<dim3(4, 8, 2), 256, 0, stream>>>(Q, R, w1, A, Bv);
    pair_gemm<<<dim3(256, 16), 256, 0, stream>>>(Q, R, A, Bv, dist, nqi, nri,
                                                 w1, b1, w2, partial);
    final_reduce<<<128, 256, 0, stream>>>(partial, b2, out);
}